// Round 6
// baseline (353.644 us; speedup 1.0000x reference)
//
#include <hip/hip_runtime.h>
#include <math.h>

#define NN 8192
#define DD 64
#define EE 64
#define NB 2
#define THRESH 0.7f
#define ISPLIT 8
#define ISPAN (NN / ISPLIT)   // 1024
#define NIT (ISPAN / 16)      // 64 iterations of 16 i
#define LOG2E 1.4426950408889634f

typedef __attribute__((ext_vector_type(8))) short bf16x8;
typedef __attribute__((ext_vector_type(4))) float f32x4;
typedef _Float16 f16x4 __attribute__((ext_vector_type(4)));
typedef __fp16 half2v __attribute__((ext_vector_type(2)));

static __device__ __forceinline__ short f2bf(float x) {  // RNE
    unsigned u = __float_as_uint(x);
    unsigned r = (u + 0x7fffu + ((u >> 16) & 1u)) >> 16;
    return (short)r;
}
static __device__ __forceinline__ unsigned pk_f16(float a, float b) {
    half2v h = __builtin_amdgcn_cvt_pkrtz(a, b);
    return __builtin_bit_cast(unsigned, h);
}
static __device__ __forceinline__ float f16lo(unsigned u) {
    half2v h = __builtin_bit_cast(half2v, u);
    return (float)h[0];
}
static __device__ __forceinline__ float f16hi(unsigned u) {
    half2v h = __builtin_bit_cast(half2v, u);
    return (float)h[1];
}

// ---------------------------------------------------------------------------
// Prep: blocks [0,512): P = U@W -> bf16, U -> bf16.
//       blocks [512,640): es16[b*64+d][i] transpose in FP16, 16B stores.
// ---------------------------------------------------------------------------
__global__ __launch_bounds__(256) void prep_kernel(const float* __restrict__ U,
                                                   const float* __restrict__ W,
                                                   const float* __restrict__ S,
                                                   const float* __restrict__ prof,
                                                   short* __restrict__ P_bf,
                                                   short* __restrict__ U_bf,
                                                   _Float16* __restrict__ es16) {
    __shared__ float smem[64 * 132 + 128];  // 34.3 KB (manual union)
    const int t = threadIdx.x;

    if (blockIdx.x < 512) {
        float* Wl = smem;
        float* Ul = smem + 4096;
        const int r0 = blockIdx.x * 16;
#pragma unroll
        for (int k = 0; k < 4; ++k)
            ((float4*)Wl)[k * 256 + t] = ((const float4*)W)[k * 256 + t];
        ((float4*)Ul)[t] = ((const float4*)U)[r0 * 16 + t];
        __syncthreads();
        const int row = t >> 4;
        const int fq = t & 15;
        const float* ur = Ul + row * EE;
        float4 acc = {0.f, 0.f, 0.f, 0.f};
#pragma unroll
        for (int e = 0; e < EE; ++e) {
            const float4 w4 = ((const float4*)Wl)[e * 16 + fq];
            const float u = ur[e];
            acc.x += u * w4.x; acc.y += u * w4.y;
            acc.z += u * w4.z; acc.w += u * w4.w;
        }
        short4 pv = {f2bf(acc.x), f2bf(acc.y), f2bf(acc.z), f2bf(acc.w)};
        *(short4*)(P_bf + (r0 + row) * EE + fq * 4) = pv;
        const float4 uv = ((const float4*)ur)[fq];
        short4 ub = {f2bf(uv.x), f2bf(uv.y), f2bf(uv.z), f2bf(uv.w)};
        *(short4*)(U_bf + (r0 + row) * EE + fq * 4) = ub;
    } else {
        float* tr = smem;           // [64][132]
        float* gl = smem + 8448;    // [128]
        const int bi = blockIdx.x - 512;  // 0..127
        const int b = bi >> 6;
        const int i0 = (bi & 63) * 128;
        if (t < 128) gl[t] = fmaxf(prof[b * NN + i0 + t] - THRESH, 0.f);
        __syncthreads();
#pragma unroll
        for (int k = 0; k < 8; ++k) {
            const int idx = k * 256 + t;  // 2048 = 128 i x 16 c4
            const int i = idx >> 4, c4 = idx & 15;
            const float g = gl[i];
            const float4 s = ((const float4*)S)[(b * NN + i0 + i) * 16 + c4];
            tr[(c4 * 4 + 0) * 132 + i] = s.x * g;
            tr[(c4 * 4 + 1) * 132 + i] = s.y * g;
            tr[(c4 * 4 + 2) * 132 + i] = s.z * g;
            tr[(c4 * 4 + 3) * 132 + i] = s.w * g;
        }
        __syncthreads();
#pragma unroll
        for (int pass = 0; pass < 4; ++pass) {
            const int row = pass * 16 + (t >> 4);
            const int ln16 = t & 15;
            const float4 a = *(const float4*)&tr[row * 132 + ln16 * 8];
            const float4 c = *(const float4*)&tr[row * 132 + ln16 * 8 + 4];
            uint4 v;
            v.x = pk_f16(a.x, a.y);
            v.y = pk_f16(a.z, a.w);
            v.z = pk_f16(c.x, c.y);
            v.w = pk_f16(c.z, c.w);
            *(uint4*)(es16 + (size_t)(b * 64 + row) * NN + i0 + ln16 * 8) = v;
        }
    }
}

// ---------------------------------------------------------------------------
// Transfer v2: BARRIER-FREE. Each wave owns one 16-j tile; iterates 16-i
// steps. K=16 f16 leak-MFMA consumes T's D-layout lane-locally (A-frag
// row=lane&15=j, k=4q+e == D row=4q+r at same lane): no LDS, no sync.
// Grid (128, ISPLIT=8) -> 1024 blocks x 4 waves; waves fully independent.
// ---------------------------------------------------------------------------
__global__ __launch_bounds__(256, 3) void transfer_kernel(const short* __restrict__ P_bf,
                                                          const short* __restrict__ U_bf,
                                                          const _Float16* __restrict__ es16,
                                                          const float* __restrict__ bias_p,
                                                          unsigned short* __restrict__ part) {
    const int t = threadIdx.x;
    const int w = t >> 6;
    const int lane = t & 63;
    const int q = lane >> 4;
    const int ln = lane & 15;
    const int jw0 = blockIdx.x * 64 + w * 16;   // this wave's j-tile
    const int i_base = blockIdx.y * ISPAN;
    const float nb = -bias_p[0] * LOG2E;
    const f32x4 zero = (f32x4){0.f, 0.f, 0.f, 0.f};

    // U B-fragments for own j-tile (T-scores mfma, K=64 via 2x K=32)
    bf16x8 uf[2];
#pragma unroll
    for (int ks = 0; ks < 2; ++ks)
        uf[ks] = *(const bf16x8*)(U_bf + (jw0 + ln) * EE + ks * 32 + q * 8);

    // leaked accumulators: acc[g] lane: (j = jw0+4q+r, bd = 16g+ln)
    f32x4 acc[8];
#pragma unroll
    for (int g = 0; g < 8; ++g) acc[g] = zero;

    f16x4 esf[8];

    auto loadP = [&](int c, bf16x8* pf) {
        const int ic = i_base + c * 16;
#pragma unroll
        for (int ks = 0; ks < 2; ++ks)
            pf[ks] = *(const bf16x8*)(P_bf + (ic + ln) * EE + ks * 32 + q * 8);
    };
    auto loadE = [&](int c) {
        const int ic = i_base + c * 16;
#pragma unroll
        for (int g = 0; g < 8; ++g)
            esf[g] = *(const f16x4*)(es16 + (size_t)(16 * g + ln) * NN + ic + 4 * q);
    };
    auto body = [&](int c, const bf16x8* pf) {
        const int ic = i_base + c * 16;
        // T tile: lane holds T[i=ic+4q+r, j=jw0+ln], r=0..3
        f32x4 s = __builtin_amdgcn_mfma_f32_16x16x32_bf16(pf[0], uf[0], zero, 0, 0, 0);
        s = __builtin_amdgcn_mfma_f32_16x16x32_bf16(pf[1], uf[1], s, 0, 0, 0);
        float T[4];
#pragma unroll
        for (int r = 0; r < 4; ++r)
            T[r] = __builtin_amdgcn_rcpf(
                1.f + __builtin_amdgcn_exp2f(fmaf(s[r], -LOG2E, nb)));
        if (ic == jw0) {  // diagonal tile (wave-uniform): zero i==j
            const int dd = ln - 4 * q;
#pragma unroll
            for (int r = 0; r < 4; ++r) T[r] = (dd == r) ? 0.f : T[r];
        }
        // pack -> fp16 A-frag for K=16 mfma (lane-local transpose!)
        uint2 pw;
        pw.x = pk_f16(T[0], T[1]);
        pw.y = pk_f16(T[2], T[3]);
        const f16x4 pa = __builtin_bit_cast(f16x4, pw);
#pragma unroll
        for (int g = 0; g < 8; ++g)
            acc[g] = __builtin_amdgcn_mfma_f32_16x16x16f16(pa, esf[g], acc[g], 0, 0, 0);
    };

    // ping-pong on pf (static names, rule #20); es loaded per-iter, latency
    // covered by the T-phase (~2 mfma + sigmoid) of the same iteration.
    bf16x8 pfa[2], pfb[2];
    loadP(0, pfa);
    for (int c = 0; c < NIT; c += 2) {
        loadE(c);
        loadP(c + 1, pfb);
        body(c, pfa);
        loadE(c + 1);
        if (c + 2 < NIT) loadP(c + 2, pfa);
        body(c + 1, pfb);
    }

    // epilogue: fp16 partials, 4KB tile per (y, jt); fully coalesced.
    const int jt = blockIdx.x * 4 + w;
    unsigned short* pb = part + (size_t)(blockIdx.y * 512 + jt) * 2048;
#pragma unroll
    for (int k = 0; k < 4; ++k) {
        uint4 v;
        v.x = pk_f16(acc[2 * k][0], acc[2 * k][1]);
        v.y = pk_f16(acc[2 * k][2], acc[2 * k][3]);
        v.z = pk_f16(acc[2 * k + 1][0], acc[2 * k + 1][1]);
        v.w = pk_f16(acc[2 * k + 1][2], acc[2 * k + 1][3]);
        *(uint4*)(pb + k * 512 + lane * 8) = v;
    }
}

// ---------------------------------------------------------------------------
// Reduce: out[b][j][d] = S + sum_y part. One block per 16-j tile (512 blocks).
// ---------------------------------------------------------------------------
__global__ __launch_bounds__(256) void reduce_kernel(const unsigned short* __restrict__ part,
                                                     const float* __restrict__ S,
                                                     float* __restrict__ out) {
    const int t = threadIdx.x;
    const int jt = blockIdx.x;   // 0..511
    const int l = t & 63, k = t >> 6;
    const int q = l >> 4, ln = l & 15;

    float acc[4][2];
#pragma unroll
    for (int c = 0; c < 4; ++c) {
        acc[c][0] = 0.f;
        acc[c][1] = 0.f;
    }

#pragma unroll
    for (int y = 0; y < ISPLIT; ++y) {
        const uint4 v = *(const uint4*)(part + (size_t)(y * 512 + jt) * 2048 + k * 512 + l * 8);
        acc[0][0] += f16lo(v.x); acc[0][1] += f16hi(v.x);
        acc[1][0] += f16lo(v.y); acc[1][1] += f16hi(v.y);
        acc[2][0] += f16lo(v.z); acc[2][1] += f16hi(v.z);
        acc[3][0] += f16lo(v.w); acc[3][1] += f16hi(v.w);
    }
#pragma unroll
    for (int c = 0; c < 4; ++c) {
        const int g = 2 * k + (c >> 1);
        const int bd = 16 * g + ln;
        const int b = bd >> 6, d = bd & 63;
#pragma unroll
        for (int h = 0; h < 2; ++h) {
            const int j = jt * 16 + 4 * q + 2 * (c & 1) + h;
            const int idx = (b * NN + j) * DD + d;
            out[idx] = S[idx] + acc[c][h];
        }
    }
}

// ---------------------------------------------------------------------------
extern "C" void kernel_launch(void* const* d_in, const int* in_sizes, int n_in,
                              void* d_out, int out_size, void* d_ws, size_t ws_size,
                              hipStream_t stream) {
    const float* states = (const float*)d_in[0];  // [B,N,D]
    const float* prof   = (const float*)d_in[1];  // [B,N]
    const float* emb    = (const float*)d_in[2];  // [N,E]
    const float* W      = (const float*)d_in[3];  // [1,E,E]
    const float* bias   = (const float*)d_in[4];  // [1]
    float* out = (float*)d_out;

    short* P_bf = (short*)d_ws;                   // 1 MB
    short* U_bf = P_bf + NN * EE;                 // 1 MB
    _Float16* es16 = (_Float16*)(U_bf + NN * EE); // 2 MB (fp16 gated states^T)
    unsigned short* part = (unsigned short*)((short*)es16 + (size_t)NB * 64 * NN);  // 16.8 MB

    prep_kernel<<<640, 256, 0, stream>>>(emb, W, states, prof, P_bf, U_bf, es16);
    transfer_kernel<<<dim3(NN / 64, ISPLIT), 256, 0, stream>>>(P_bf, U_bf, es16, bias, part);
    reduce_kernel<<<512, 256, 0, stream>>>(part, states, out);
}

// Round 7
// 114.589 us; speedup vs baseline: 3.0862x; 3.0862x over previous
//
#include <hip/hip_runtime.h>
#include <math.h>

#define NN 8192
#define DD 64
#define EE 64
#define NB 2
#define THRESH 0.7f
#define JT 64
#define IC 64
#define ISPLIT 8
#define ISPAN (NN / ISPLIT)
#define LOG2E 1.4426950408889634f

typedef __attribute__((ext_vector_type(8))) short bf16x8;
typedef __attribute__((ext_vector_type(4))) float f32x4;
typedef __fp16 half2v __attribute__((ext_vector_type(2)));

static __device__ __forceinline__ short f2bf(float x) {  // RNE
    unsigned u = __float_as_uint(x);
    unsigned r = (u + 0x7fffu + ((u >> 16) & 1u)) >> 16;
    return (short)r;
}
static __device__ __forceinline__ unsigned pack_bf_trunc(float lo, float hi) {
    return __builtin_amdgcn_perm(__float_as_uint(hi), __float_as_uint(lo), 0x07060302u);
}
static __device__ __forceinline__ unsigned pk_f16(float a, float b) {
    half2v h = __builtin_amdgcn_cvt_pkrtz(a, b);
    return __builtin_bit_cast(unsigned, h);
}
static __device__ __forceinline__ float f16lo(unsigned u) {
    half2v h = __builtin_bit_cast(half2v, u);
    return (float)h[0];
}
static __device__ __forceinline__ float f16hi(unsigned u) {
    half2v h = __builtin_bit_cast(half2v, u);
    return (float)h[1];
}

// ---------------------------------------------------------------------------
// Prep: blocks [0,512): P = U@W -> bf16, U -> bf16.
//       blocks [512,640): es in FRAGMENT-MAJOR tiles es_f[cg][g][ks][lane][8]
//       (lane=16q+ln holds es[bd=(g>>2)*64+(g&3)*16+ln][cg*64+ks*32+q*8+e]).
//       Old row-major [bd][i] layout had 16KB lane-stride gathers in the
//       transfer kernel -> L2-channel serialization (round-6 diagnosis).
// ---------------------------------------------------------------------------
__global__ __launch_bounds__(256) void prep_kernel(const float* __restrict__ U,
                                                   const float* __restrict__ W,
                                                   const float* __restrict__ S,
                                                   const float* __restrict__ prof,
                                                   short* __restrict__ P_bf,
                                                   short* __restrict__ U_bf,
                                                   short* __restrict__ es_f) {
    __shared__ float smem[64 * 132 + 128];  // 34.3 KB (manual union)
    const int t = threadIdx.x;

    if (blockIdx.x < 512) {
        float* Wl = smem;
        float* Ul = smem + 4096;
        const int r0 = blockIdx.x * 16;
#pragma unroll
        for (int k = 0; k < 4; ++k)
            ((float4*)Wl)[k * 256 + t] = ((const float4*)W)[k * 256 + t];
        ((float4*)Ul)[t] = ((const float4*)U)[r0 * 16 + t];
        __syncthreads();
        const int row = t >> 4;
        const int fq = t & 15;
        const float* ur = Ul + row * EE;
        float4 acc = {0.f, 0.f, 0.f, 0.f};
#pragma unroll
        for (int e = 0; e < EE; ++e) {
            const float4 w4 = ((const float4*)Wl)[e * 16 + fq];
            const float u = ur[e];
            acc.x += u * w4.x; acc.y += u * w4.y;
            acc.z += u * w4.z; acc.w += u * w4.w;
        }
        short4 pv = {f2bf(acc.x), f2bf(acc.y), f2bf(acc.z), f2bf(acc.w)};
        *(short4*)(P_bf + (r0 + row) * EE + fq * 4) = pv;
        const float4 uv = ((const float4*)ur)[fq];
        short4 ub = {f2bf(uv.x), f2bf(uv.y), f2bf(uv.z), f2bf(uv.w)};
        *(short4*)(U_bf + (r0 + row) * EE + fq * 4) = ub;
    } else {
        float* tr = smem;           // [64][132]
        float* gl = smem + 8448;    // [128]
        const int bi = blockIdx.x - 512;  // 0..127
        const int b = bi >> 6;
        const int i0 = (bi & 63) * 128;
        if (t < 128) gl[t] = fmaxf(prof[b * NN + i0 + t] - THRESH, 0.f);
        __syncthreads();
#pragma unroll
        for (int k = 0; k < 8; ++k) {
            const int idx = k * 256 + t;  // 2048 = 128 i x 16 c4
            const int i = idx >> 4, c4 = idx & 15;
            const float g = gl[i];
            const float4 s = ((const float4*)S)[(b * NN + i0 + i) * 16 + c4];
            tr[(c4 * 4 + 0) * 132 + i] = s.x * g;
            tr[(c4 * 4 + 1) * 132 + i] = s.y * g;
            tr[(c4 * 4 + 2) * 132 + i] = s.z * g;
            tr[(c4 * 4 + 3) * 132 + i] = s.w * g;
        }
        __syncthreads();
#pragma unroll
        for (int pass = 0; pass < 4; ++pass) {
            const int d = pass * 16 + (t >> 4);   // within-b row 0..63
            const int i8 = t & 15;                // 8-element i-group 0..15
            const float4 a = *(const float4*)&tr[d * 132 + i8 * 8];
            const float4 c = *(const float4*)&tr[d * 132 + i8 * 8 + 4];
            bf16x8 v;
            v[0] = f2bf(a.x); v[1] = f2bf(a.y); v[2] = f2bf(a.z); v[3] = f2bf(a.w);
            v[4] = f2bf(c.x); v[5] = f2bf(c.y); v[6] = f2bf(c.z); v[7] = f2bf(c.w);
            // fragment-major address
            const int cg = (bi & 63) * 2 + (i8 >> 3);  // 64-i chunk
            const int ks = (i8 >> 2) & 1;
            const int q  = i8 & 3;
            const int g  = b * 4 + (d >> 4);
            const int lane = q * 16 + (d & 15);
            *(bf16x8*)(es_f + ((((cg * 8 + g) * 2 + ks) << 9) + lane * 8)) = v;
        }
    }
}

// ---------------------------------------------------------------------------
// Transfer: grid (N/JT=128, ISPLIT=8), 256 threads. R0 structure (proven
// 58us) with COALESCED es loads: each load_es instruction reads a contiguous
// 1KB fragment tile (was a 16KB-stride 16-line gather).
// ---------------------------------------------------------------------------
__global__ __launch_bounds__(256, 3) void transfer_kernel(const short* __restrict__ P_bf,
                                                          const short* __restrict__ U_bf,
                                                          const short* __restrict__ es_f,
                                                          const float* __restrict__ bias_p,
                                                          unsigned short* __restrict__ part) {
    // T in MFMA-A fragment order, double-buffered: [buf][tile][lane][8 shorts]
    __shared__ __align__(16) short TT[2][8 * 64 * 8];  // 16 KB

    const int t = threadIdx.x;
    const int w = t >> 6;
    const int lane = t & 63;
    const int q = lane >> 4;
    const int ln = lane & 15;
    const int j0 = blockIdx.x * JT;
    const int i_base = blockIdx.y * ISPAN;
    const int cg_base = blockIdx.y * (ISPAN / 64);
    const float nb = -bias_p[0] * LOG2E;

    // U B-fragments resident for the whole kernel
    bf16x8 uf[4][2];
#pragma unroll
    for (int jt = 0; jt < 4; ++jt)
#pragma unroll
        for (int ks = 0; ks < 2; ++ks)
            uf[jt][ks] = *(const bf16x8*)(U_bf + (j0 + jt * 16 + ln) * EE + ks * 32 + q * 8);

    f32x4 acc[4][2];
#pragma unroll
    for (int jm = 0; jm < 4; ++jm)
#pragma unroll
        for (int c = 0; c < 2; ++c) acc[jm][c] = (f32x4){0.f, 0.f, 0.f, 0.f};
    const f32x4 zero = (f32x4){0.f, 0.f, 0.f, 0.f};

    // producer TT slot: i_local=16w+4q+r -> ks=(w>>1), q'=(2w+(q>>1))&3, half=(q&1)
    const int ks_w = w >> 1;
    const int qp = (2 * w + (q >> 1)) & 3;
    const int ttw_off = (ks_w * 64 + qp * 16 + ln) * 2 + (q & 1);  // uint2 units

    auto load_p = [&](int cc, bf16x8* pf) {
        const int i0 = i_base + cc * IC;
#pragma unroll
        for (int ks = 0; ks < 2; ++ks)
            pf[ks] = *(const bf16x8*)(P_bf + (i0 + w * 16 + ln) * EE + ks * 32 + q * 8);
    };
    auto load_es = [&](int cc, bf16x8 (*bfr)[2]) {
        const int cg = cg_base + cc;
#pragma unroll
        for (int c = 0; c < 2; ++c) {
            const int g = w * 2 + c;
            const short* er = es_f + (((cg * 8 + g) * 2) << 9) + lane * 8;
#pragma unroll
            for (int ks = 0; ks < 2; ++ks)
                bfr[c][ks] = *(const bf16x8*)(er + (ks << 9));
        }
    };
    auto phase_a = [&](int cc, const bf16x8* pf, short* tt) {
        const int i0 = i_base + cc * IC;
        const bool dg = (i0 == j0);
#pragma unroll
        for (int jt = 0; jt < 4; ++jt) {
            f32x4 s = __builtin_amdgcn_mfma_f32_16x16x32_bf16(pf[0], uf[jt][0], zero, 0, 0, 0);
            s = __builtin_amdgcn_mfma_f32_16x16x32_bf16(pf[1], uf[jt][1], s, 0, 0, 0);
            float T[4];
#pragma unroll
            for (int r = 0; r < 4; ++r)
                T[r] = __builtin_amdgcn_rcpf(
                    1.f + __builtin_amdgcn_exp2f(fmaf(s[r], -LOG2E, nb)));
            if (dg && jt == w) {  // diagonal 16x16 sub-tile
                const int rr = ln - 4 * q;
                if (rr >= 0 && rr < 4) T[rr] = 0.f;
            }
            uint2 pk;
            pk.x = pack_bf_trunc(T[0], T[1]);
            pk.y = pack_bf_trunc(T[2], T[3]);
            ((uint2*)tt)[jt * 256 + ttw_off] = pk;
        }
    };
    auto phase_b = [&](const bf16x8 (*bfr)[2], const short* tt) {
#pragma unroll
        for (int jm = 0; jm < 4; ++jm)
#pragma unroll
            for (int ks = 0; ks < 2; ++ks) {
                const bf16x8 af = *(const bf16x8*)(tt + ((jm * 2 + ks) * 64 + lane) * 8);
                acc[jm][0] = __builtin_amdgcn_mfma_f32_16x16x32_bf16(af, bfr[0][ks], acc[jm][0], 0, 0, 0);
                acc[jm][1] = __builtin_amdgcn_mfma_f32_16x16x32_bf16(af, bfr[1][ks], acc[jm][1], 0, 0, 0);
            }
    };

    // prologue
    bf16x8 pfA[2], pfB[2], bfA[2][2], bfB[2][2];
    load_p(0, pfA);
    load_es(0, bfA);
    load_p(1, pfB);
    phase_a(0, pfA, TT[0]);
    __syncthreads();  // TT[0] ready

    const int NCH = ISPAN / IC;  // 16
#pragma unroll
    for (int c = 0; c < NCH; c += 2) {
        // even iter: A(c+1)->TT1 || B(c)<-TT0
        if (c + 1 < NCH) load_es(c + 1, bfB);
        if (c + 2 < NCH) load_p(c + 2, pfA);
        if (c + 1 < NCH) phase_a(c + 1, pfB, TT[1]);
        phase_b(bfA, TT[0]);
        __syncthreads();
        // odd iter: A(c+2)->TT0 || B(c+1)<-TT1
        if (c + 2 < NCH) load_es(c + 2, bfA);
        if (c + 3 < NCH) load_p(c + 3, pfB);
        if (c + 2 < NCH) phase_a(c + 2, pfA, TT[0]);
        if (c + 1 < NCH) phase_b(bfB, TT[1]);
        __syncthreads();
    }

    // epilogue: fp16 partials in [jm-plane][thread] layout (coalesced both ways)
    unsigned short* pb = part + (size_t)(blockIdx.y * (NN / JT) + blockIdx.x) * 8192;
#pragma unroll
    for (int jm = 0; jm < 4; ++jm) {
        uint4 v;
        v.x = pk_f16(acc[jm][0][0], acc[jm][0][1]);
        v.y = pk_f16(acc[jm][0][2], acc[jm][0][3]);
        v.z = pk_f16(acc[jm][1][0], acc[jm][1][1]);
        v.w = pk_f16(acc[jm][1][2], acc[jm][1][3]);
        *(uint4*)(pb + jm * 2048 + t * 8) = v;
    }
}

// ---------------------------------------------------------------------------
// Reduce: out[b][j][d] = state + sum_y partial_y. grid (128, 2) x 256.
// ---------------------------------------------------------------------------
__global__ __launch_bounds__(256) void reduce_kernel(const unsigned short* __restrict__ part,
                                                     const float* __restrict__ S,
                                                     float* __restrict__ out) {
    const int t = threadIdx.x;
    const int jx = blockIdx.x;  // 0..127
    const int s = blockIdx.y;   // 0..1
    const int w = t >> 6, lane = t & 63, q = lane >> 4, ln = lane & 15;

    float acc[2][2][4];
#pragma unroll
    for (int jj = 0; jj < 2; ++jj)
#pragma unroll
        for (int c = 0; c < 2; ++c)
#pragma unroll
            for (int r = 0; r < 4; ++r) acc[jj][c][r] = 0.f;

#pragma unroll
    for (int y = 0; y < ISPLIT; ++y) {
        const unsigned short* pb = part + (size_t)(y * (NN / JT) + jx) * 8192;
#pragma unroll
        for (int jj = 0; jj < 2; ++jj) {
            const int jm = s * 2 + jj;
            const uint4 v = *(const uint4*)(pb + jm * 2048 + t * 8);  // coalesced
            acc[jj][0][0] += f16lo(v.x); acc[jj][0][1] += f16hi(v.x);
            acc[jj][0][2] += f16lo(v.y); acc[jj][0][3] += f16hi(v.y);
            acc[jj][1][0] += f16lo(v.z); acc[jj][1][1] += f16hi(v.z);
            acc[jj][1][2] += f16lo(v.w); acc[jj][1][3] += f16hi(v.w);
        }
    }
#pragma unroll
    for (int jj = 0; jj < 2; ++jj)
#pragma unroll
        for (int c = 0; c < 2; ++c) {
            const int g = w * 2 + c;
            const int bb = g >> 2, dt = g & 3;
            const int j = jx * 64 + (s * 2 + jj) * 16 + q * 4;
#pragma unroll
            for (int r = 0; r < 4; ++r) {
                const int idx = (bb * NN + j + r) * DD + dt * 16 + ln;
                out[idx] = S[idx] + acc[jj][c][r];
            }
        }
}

// ---------------------------------------------------------------------------
extern "C" void kernel_launch(void* const* d_in, const int* in_sizes, int n_in,
                              void* d_out, int out_size, void* d_ws, size_t ws_size,
                              hipStream_t stream) {
    const float* states = (const float*)d_in[0];  // [B,N,D]
    const float* prof   = (const float*)d_in[1];  // [B,N]
    const float* emb    = (const float*)d_in[2];  // [N,E]
    const float* W      = (const float*)d_in[3];  // [1,E,E]
    const float* bias   = (const float*)d_in[4];  // [1]
    float* out = (float*)d_out;

    short* P_bf = (short*)d_ws;                 // 1 MB
    short* U_bf = P_bf + NN * EE;               // 1 MB
    short* es_f = U_bf + NN * EE;               // 2 MB (fragment-major tiles)
    unsigned short* part = (unsigned short*)(es_f + (size_t)NB * 64 * NN);  // 16.8 MB

    prep_kernel<<<640, 256, 0, stream>>>(emb, W, states, prof, P_bf, U_bf, es_f);
    transfer_kernel<<<dim3(NN / JT, ISPLIT), 256, 0, stream>>>(P_bf, U_bf, es_f, bias, part);
    reduce_kernel<<<dim3(NN / JT, 2), 256, 0, stream>>>(part, states, out);
}

// Round 8
// 108.114 us; speedup vs baseline: 3.2710x; 1.0599x over previous
//
#include <hip/hip_runtime.h>
#include <math.h>

#define NN 8192
#define DD 64
#define EE 64
#define NB 2
#define THRESH 0.7f
#define JT 64
#define IC 64
#define ISPLIT 8
#define ISPAN (NN / ISPLIT)
#define LOG2E 1.4426950408889634f

typedef __attribute__((ext_vector_type(8))) short bf16x8;
typedef __attribute__((ext_vector_type(4))) float f32x4;
typedef __fp16 half2v __attribute__((ext_vector_type(2)));

static __device__ __forceinline__ short f2bf(float x) {  // RNE
    unsigned u = __float_as_uint(x);
    unsigned r = (u + 0x7fffu + ((u >> 16) & 1u)) >> 16;
    return (short)r;
}
static __device__ __forceinline__ unsigned pack_bf_trunc(float lo, float hi) {
    return __builtin_amdgcn_perm(__float_as_uint(hi), __float_as_uint(lo), 0x07060302u);
}
static __device__ __forceinline__ unsigned pk_f16(float a, float b) {
    half2v h = __builtin_amdgcn_cvt_pkrtz(a, b);
    return __builtin_bit_cast(unsigned, h);
}
static __device__ __forceinline__ float f16lo(unsigned u) {
    half2v h = __builtin_bit_cast(half2v, u);
    return (float)h[0];
}
static __device__ __forceinline__ float f16hi(unsigned u) {
    half2v h = __builtin_bit_cast(half2v, u);
    return (float)h[1];
}

// ---------------------------------------------------------------------------
// Prep v2: blocks [0,128): P = U@W via MFMA (was 512-block serial fp32 loop)
//          + U -> bf16 conversion from the same loaded data.
//          blocks [128,256): es in FRAGMENT-MAJOR tiles es_f[cg][g][ks][lane][8]
//          (round-7 layout; coalesced consumer loads).
// ---------------------------------------------------------------------------
__global__ __launch_bounds__(256) void prep_kernel(const float* __restrict__ U,
                                                   const float* __restrict__ W,
                                                   const float* __restrict__ S,
                                                   const float* __restrict__ prof,
                                                   short* __restrict__ P_bf,
                                                   short* __restrict__ U_bf,
                                                   short* __restrict__ es_f) {
    __shared__ float smem[64 * 132 + 128];  // 34.3 KB (covers both roles)
    const int t = threadIdx.x;
    const f32x4 zero = (f32x4){0.f, 0.f, 0.f, 0.f};

    if (blockIdx.x < 128) {
        // ---- P = U@W with 16x16x32 bf16 MFMA ----
        float* WT = smem;  // [64][68] transposed W, +68 pad: float4-aligned,
                           // 2-way bank alias only (free, m136)
        for (int x = 0; x < 16; ++x) {
            const int idx = x * 256 + t;     // idx = k*64 + f
            const int k = idx >> 6, f = idx & 63;
            WT[f * 68 + k] = W[idx];
        }
        __syncthreads();

        const int w = t >> 6, lane = t & 63, q = lane >> 4, ln = lane & 15;
        const int r0 = blockIdx.x * 64 + w * 16;

        // A-frags from U rows (lane ln <-> row r0+ln); also emit U_bf.
        bf16x8 a[2];
#pragma unroll
        for (int ks = 0; ks < 2; ++ks) {
            const float4 u0 = *(const float4*)(U + (r0 + ln) * EE + ks * 32 + q * 8);
            const float4 u1 = *(const float4*)(U + (r0 + ln) * EE + ks * 32 + q * 8 + 4);
            bf16x8 v;
            v[0] = f2bf(u0.x); v[1] = f2bf(u0.y); v[2] = f2bf(u0.z); v[3] = f2bf(u0.w);
            v[4] = f2bf(u1.x); v[5] = f2bf(u1.y); v[6] = f2bf(u1.z); v[7] = f2bf(u1.w);
            a[ks] = v;
            *(bf16x8*)(U_bf + (r0 + ln) * EE + ks * 32 + q * 8) = v;
        }
        // B-frags from W^T rows (lane ln <-> col f = ct*16+ln).
        bf16x8 b[4][2];
#pragma unroll
        for (int ct = 0; ct < 4; ++ct)
#pragma unroll
            for (int ks = 0; ks < 2; ++ks) {
                const float* wp = WT + (ct * 16 + ln) * 68 + ks * 32 + q * 8;
                const float4 w0 = *(const float4*)wp;
                const float4 w1 = *(const float4*)(wp + 4);
                bf16x8 v;
                v[0] = f2bf(w0.x); v[1] = f2bf(w0.y); v[2] = f2bf(w0.z); v[3] = f2bf(w0.w);
                v[4] = f2bf(w1.x); v[5] = f2bf(w1.y); v[6] = f2bf(w1.z); v[7] = f2bf(w1.w);
                b[ct][ks] = v;
            }
#pragma unroll
        for (int ct = 0; ct < 4; ++ct) {
            f32x4 s = __builtin_amdgcn_mfma_f32_16x16x32_bf16(a[0], b[ct][0], zero, 0, 0, 0);
            s = __builtin_amdgcn_mfma_f32_16x16x32_bf16(a[1], b[ct][1], s, 0, 0, 0);
#pragma unroll
            for (int r = 0; r < 4; ++r)
                P_bf[(r0 + 4 * q + r) * EE + ct * 16 + ln] = f2bf(s[r]);
        }
    } else {
        float* tr = smem;           // [64][132]
        float* gl = smem + 8448;    // [128]
        const int bi = blockIdx.x - 128;  // 0..127
        const int b = bi >> 6;
        const int i0 = (bi & 63) * 128;
        if (t < 128) gl[t] = fmaxf(prof[b * NN + i0 + t] - THRESH, 0.f);
        __syncthreads();
#pragma unroll
        for (int k = 0; k < 8; ++k) {
            const int idx = k * 256 + t;  // 2048 = 128 i x 16 c4
            const int i = idx >> 4, c4 = idx & 15;
            const float g = gl[i];
            const float4 s = ((const float4*)S)[(b * NN + i0 + i) * 16 + c4];
            tr[(c4 * 4 + 0) * 132 + i] = s.x * g;
            tr[(c4 * 4 + 1) * 132 + i] = s.y * g;
            tr[(c4 * 4 + 2) * 132 + i] = s.z * g;
            tr[(c4 * 4 + 3) * 132 + i] = s.w * g;
        }
        __syncthreads();
#pragma unroll
        for (int pass = 0; pass < 4; ++pass) {
            const int d = pass * 16 + (t >> 4);   // within-b row 0..63
            const int i8 = t & 15;                // 8-element i-group 0..15
            const float4 a = *(const float4*)&tr[d * 132 + i8 * 8];
            const float4 c = *(const float4*)&tr[d * 132 + i8 * 8 + 4];
            bf16x8 v;
            v[0] = f2bf(a.x); v[1] = f2bf(a.y); v[2] = f2bf(a.z); v[3] = f2bf(a.w);
            v[4] = f2bf(c.x); v[5] = f2bf(c.y); v[6] = f2bf(c.z); v[7] = f2bf(c.w);
            // fragment-major address
            const int cg = (bi & 63) * 2 + (i8 >> 3);  // 64-i chunk
            const int ks = (i8 >> 2) & 1;
            const int q  = i8 & 3;
            const int g  = b * 4 + (d >> 4);
            const int lane = q * 16 + (d & 15);
            *(bf16x8*)(es_f + ((((cg * 8 + g) * 2 + ks) << 9) + lane * 8)) = v;
        }
    }
}

// ---------------------------------------------------------------------------
// Transfer: UNCHANGED from round 7 (verified winner): grid (128, 8), 256 thr,
// fragment-major coalesced es loads, LDS TT exchange, double-buffered.
// ---------------------------------------------------------------------------
__global__ __launch_bounds__(256, 3) void transfer_kernel(const short* __restrict__ P_bf,
                                                          const short* __restrict__ U_bf,
                                                          const short* __restrict__ es_f,
                                                          const float* __restrict__ bias_p,
                                                          unsigned short* __restrict__ part) {
    // T in MFMA-A fragment order, double-buffered: [buf][tile][lane][8 shorts]
    __shared__ __align__(16) short TT[2][8 * 64 * 8];  // 16 KB

    const int t = threadIdx.x;
    const int w = t >> 6;
    const int lane = t & 63;
    const int q = lane >> 4;
    const int ln = lane & 15;
    const int j0 = blockIdx.x * JT;
    const int i_base = blockIdx.y * ISPAN;
    const int cg_base = blockIdx.y * (ISPAN / 64);
    const float nb = -bias_p[0] * LOG2E;

    // U B-fragments resident for the whole kernel
    bf16x8 uf[4][2];
#pragma unroll
    for (int jt = 0; jt < 4; ++jt)
#pragma unroll
        for (int ks = 0; ks < 2; ++ks)
            uf[jt][ks] = *(const bf16x8*)(U_bf + (j0 + jt * 16 + ln) * EE + ks * 32 + q * 8);

    f32x4 acc[4][2];
#pragma unroll
    for (int jm = 0; jm < 4; ++jm)
#pragma unroll
        for (int c = 0; c < 2; ++c) acc[jm][c] = (f32x4){0.f, 0.f, 0.f, 0.f};
    const f32x4 zero = (f32x4){0.f, 0.f, 0.f, 0.f};

    // producer TT slot: i_local=16w+4q+r -> ks=(w>>1), q'=(2w+(q>>1))&3, half=(q&1)
    const int ks_w = w >> 1;
    const int qp = (2 * w + (q >> 1)) & 3;
    const int ttw_off = (ks_w * 64 + qp * 16 + ln) * 2 + (q & 1);  // uint2 units

    auto load_p = [&](int cc, bf16x8* pf) {
        const int i0 = i_base + cc * IC;
#pragma unroll
        for (int ks = 0; ks < 2; ++ks)
            pf[ks] = *(const bf16x8*)(P_bf + (i0 + w * 16 + ln) * EE + ks * 32 + q * 8);
    };
    auto load_es = [&](int cc, bf16x8 (*bfr)[2]) {
        const int cg = cg_base + cc;
#pragma unroll
        for (int c = 0; c < 2; ++c) {
            const int g = w * 2 + c;
            const short* er = es_f + (((cg * 8 + g) * 2) << 9) + lane * 8;
#pragma unroll
            for (int ks = 0; ks < 2; ++ks)
                bfr[c][ks] = *(const bf16x8*)(er + (ks << 9));
        }
    };
    auto phase_a = [&](int cc, const bf16x8* pf, short* tt) {
        const int i0 = i_base + cc * IC;
        const bool dg = (i0 == j0);
#pragma unroll
        for (int jt = 0; jt < 4; ++jt) {
            f32x4 s = __builtin_amdgcn_mfma_f32_16x16x32_bf16(pf[0], uf[jt][0], zero, 0, 0, 0);
            s = __builtin_amdgcn_mfma_f32_16x16x32_bf16(pf[1], uf[jt][1], s, 0, 0, 0);
            float T[4];
#pragma unroll
            for (int r = 0; r < 4; ++r)
                T[r] = __builtin_amdgcn_rcpf(
                    1.f + __builtin_amdgcn_exp2f(fmaf(s[r], -LOG2E, nb)));
            if (dg && jt == w) {  // diagonal 16x16 sub-tile
                const int rr = ln - 4 * q;
                if (rr >= 0 && rr < 4) T[rr] = 0.f;
            }
            uint2 pk;
            pk.x = pack_bf_trunc(T[0], T[1]);
            pk.y = pack_bf_trunc(T[2], T[3]);
            ((uint2*)tt)[jt * 256 + ttw_off] = pk;
        }
    };
    auto phase_b = [&](const bf16x8 (*bfr)[2], const short* tt) {
#pragma unroll
        for (int jm = 0; jm < 4; ++jm)
#pragma unroll
            for (int ks = 0; ks < 2; ++ks) {
                const bf16x8 af = *(const bf16x8*)(tt + ((jm * 2 + ks) * 64 + lane) * 8);
                acc[jm][0] = __builtin_amdgcn_mfma_f32_16x16x32_bf16(af, bfr[0][ks], acc[jm][0], 0, 0, 0);
                acc[jm][1] = __builtin_amdgcn_mfma_f32_16x16x32_bf16(af, bfr[1][ks], acc[jm][1], 0, 0, 0);
            }
    };

    // prologue
    bf16x8 pfA[2], pfB[2], bfA[2][2], bfB[2][2];
    load_p(0, pfA);
    load_es(0, bfA);
    load_p(1, pfB);
    phase_a(0, pfA, TT[0]);
    __syncthreads();  // TT[0] ready

    const int NCH = ISPAN / IC;  // 16
#pragma unroll
    for (int c = 0; c < NCH; c += 2) {
        // even iter: A(c+1)->TT1 || B(c)<-TT0
        if (c + 1 < NCH) load_es(c + 1, bfB);
        if (c + 2 < NCH) load_p(c + 2, pfA);
        if (c + 1 < NCH) phase_a(c + 1, pfB, TT[1]);
        phase_b(bfA, TT[0]);
        __syncthreads();
        // odd iter: A(c+2)->TT0 || B(c+1)<-TT1
        if (c + 2 < NCH) load_es(c + 2, bfA);
        if (c + 3 < NCH) load_p(c + 3, pfB);
        if (c + 2 < NCH) phase_a(c + 2, pfA, TT[0]);
        if (c + 1 < NCH) phase_b(bfB, TT[1]);
        __syncthreads();
    }

    // epilogue: fp16 partials in [jm-plane][thread] layout (coalesced both ways)
    unsigned short* pb = part + (size_t)(blockIdx.y * (NN / JT) + blockIdx.x) * 8192;
#pragma unroll
    for (int jm = 0; jm < 4; ++jm) {
        uint4 v;
        v.x = pk_f16(acc[jm][0][0], acc[jm][0][1]);
        v.y = pk_f16(acc[jm][0][2], acc[jm][0][3]);
        v.z = pk_f16(acc[jm][1][0], acc[jm][1][1]);
        v.w = pk_f16(acc[jm][1][2], acc[jm][1][3]);
        *(uint4*)(pb + jm * 2048 + t * 8) = v;
    }
}

// ---------------------------------------------------------------------------
// Reduce: out[b][j][d] = state + sum_y partial_y. grid (128, 4) x 256
// (512 blocks, one jm-plane each — round-3/4-verified variant).
// ---------------------------------------------------------------------------
__global__ __launch_bounds__(256) void reduce_kernel(const unsigned short* __restrict__ part,
                                                     const float* __restrict__ S,
                                                     float* __restrict__ out) {
    const int t = threadIdx.x;
    const int jx = blockIdx.x;   // 0..127
    const int jm = blockIdx.y;   // 0..3
    const int w = t >> 6, lane = t & 63, q = lane >> 4, ln = lane & 15;

    float acc[2][4];
#pragma unroll
    for (int c = 0; c < 2; ++c)
#pragma unroll
        for (int r = 0; r < 4; ++r) acc[c][r] = 0.f;

#pragma unroll
    for (int y = 0; y < ISPLIT; ++y) {
        const unsigned short* pb = part + (size_t)(y * (NN / JT) + jx) * 8192;
        const uint4 v = *(const uint4*)(pb + jm * 2048 + t * 8);  // coalesced
        acc[0][0] += f16lo(v.x); acc[0][1] += f16hi(v.x);
        acc[0][2] += f16lo(v.y); acc[0][3] += f16hi(v.y);
        acc[1][0] += f16lo(v.z); acc[1][1] += f16hi(v.z);
        acc[1][2] += f16lo(v.w); acc[1][3] += f16hi(v.w);
    }
#pragma unroll
    for (int c = 0; c < 2; ++c) {
        const int g = w * 2 + c;
        const int bb = g >> 2, dt = g & 3;
        const int j = jx * 64 + jm * 16 + q * 4;
#pragma unroll
        for (int r = 0; r < 4; ++r) {
            const int idx = (bb * NN + j + r) * DD + dt * 16 + ln;
            out[idx] = S[idx] + acc[c][r];
        }
    }
}

// ---------------------------------------------------------------------------
extern "C" void kernel_launch(void* const* d_in, const int* in_sizes, int n_in,
                              void* d_out, int out_size, void* d_ws, size_t ws_size,
                              hipStream_t stream) {
    const float* states = (const float*)d_in[0];  // [B,N,D]
    const float* prof   = (const float*)d_in[1];  // [B,N]
    const float* emb    = (const float*)d_in[2];  // [N,E]
    const float* W      = (const float*)d_in[3];  // [1,E,E]
    const float* bias   = (const float*)d_in[4];  // [1]
    float* out = (float*)d_out;

    short* P_bf = (short*)d_ws;                 // 1 MB
    short* U_bf = P_bf + NN * EE;               // 1 MB
    short* es_f = U_bf + NN * EE;               // 2 MB (fragment-major tiles)
    unsigned short* part = (unsigned short*)(es_f + (size_t)NB * 64 * NN);  // 16.8 MB

    prep_kernel<<<256, 256, 0, stream>>>(emb, W, states, prof, P_bf, U_bf, es_f);
    transfer_kernel<<<dim3(NN / JT, ISPLIT), 256, 0, stream>>>(P_bf, U_bf, es_f, bias, part);
    reduce_kernel<<<dim3(NN / JT, 4), 256, 0, stream>>>(part, states, out);
}